// Round 16
// baseline (96.993 us; speedup 1.0000x reference)
//
#include <hip/hip_runtime.h>
#include <hip/hip_bf16.h>

// LocalKNN: B=64, Way=5, D=64, Nq=1024, Ns=1024, K=3.
// out[b,w] = sum_q rnq[q] * sum(top3_s( <q_bq, shat_bws> ))
// Round 16: (1) amdgpu_waves_per_eu(1,2) -> occupancy TARGET 2 waves/EU so the
// allocator stops AGPR-parking state (VGPR_Count stuck at 52 for 5 rounds with
// >52 live values = hidden AGPR shuttling + serialized schedule).
// (2) hand-written 3-stage pipeline, fully unrolled, named regs: per tile t:
// stage(t+3) -> vmcnt(4) [t+1 ready] -> ds_read(t+1)->aN -> MFMA(t) from aC ->
// INS(t-1) from cP. Consumers one full iteration behind producers, so the
// ds_read(120cy)/MFMA(40cy) latencies hide under the previous tile's INS work.

using bf16x8 = __attribute__((ext_vector_type(8))) short;  // 8 bf16 = 4 VGPRs
using f32x4  = __attribute__((ext_vector_type(4))) float;

__device__ inline unsigned cvt_pk_bf16(float lo, float hi) {
    unsigned r;
    asm("v_cvt_pk_bf16_f32 %0, %1, %2" : "=v"(r) : "v"(lo), "v"(hi));
    return r;
}

__device__ inline uint4 pack8cvt(const float* v) {
    uint4 r;
    r.x = cvt_pk_bf16(v[0], v[1]);
    r.y = cvt_pk_bf16(v[2], v[3]);
    r.z = cvt_pk_bf16(v[4], v[5]);
    r.w = cvt_pk_bf16(v[6], v[7]);
    return r;
}

// branchless insert of v into sorted top-3 (t0>=t1>=t2): 1 max + 2 med3
#define INS(v, T0, T1, T2) do {                         \
    float _v = (v);                                     \
    float _n0 = fmaxf((T0), _v);                        \
    float _n1 = __builtin_amdgcn_fmed3f(_v, (T0), (T1));\
    float _n2 = __builtin_amdgcn_fmed3f(_v, (T1), (T2));\
    (T0) = _n0; (T1) = _n1; (T2) = _n2;                 \
} while (0)

// async 16B/lane global->LDS (LDS dest = wave-uniform base + lane*16)
__device__ inline void gload16(const void* g, void* lds) {
    __builtin_amdgcn_global_load_lds(
        (const __attribute__((address_space(1))) unsigned int*)g,
        (__attribute__((address_space(3))) unsigned int*)lds,
        16, 0, 0);
}

// ============================= fast path =====================================
// Fragment layout: per 16-col tile, 128 uint4 slots; slot h*16 + r holds
// column (tile*16+r)'s elements d = 8h..8h+7 as 4 packed bf16-pairs.

// ---- prep_all: raw Q/S -> bf16 fragments (+ rnq) ----------------------------
__global__ __launch_bounds__(256) void prep_all(const float* __restrict__ Q,
                                                const float* __restrict__ S,
                                                uint4* __restrict__ Qbf,
                                                uint4* __restrict__ Sbf,
                                                float* __restrict__ rnq) {
    const int blk = blockIdx.x;
    if (blk < 256) {
        const int b = blk >> 2;
        const int col = ((blk & 3) << 8) + threadIdx.x;      // q in 0..1023
        const float* p = Q + (size_t)b * 65536 + col;
        float v[64];
        #pragma unroll
        for (int d = 0; d < 64; ++d) v[d] = p[(size_t)d << 10];
        float ss = 0.f;
        #pragma unroll
        for (int d = 0; d < 64; ++d) ss += v[d] * v[d];
        rnq[(b << 10) + col] = 1.0f / fmaxf(sqrtf(ss), 1e-12f);
        uint4* ob = Qbf + ((size_t)(b << 6) + (col >> 4)) * 128 + (col & 15);
        #pragma unroll
        for (int h = 0; h < 8; ++h)
            ob[h << 4] = pack8cvt(&v[h << 3]);
    } else {
        const int bw = (blk - 256) >> 2;
        const int col = ((blk & 3) << 8) + threadIdx.x;      // s in 0..1023
        const float* p = S + (size_t)bw * 65536 + col;
        float v[64];
        #pragma unroll
        for (int d = 0; d < 64; ++d) v[d] = p[(size_t)d << 10];
        float ss = 0.f;
        #pragma unroll
        for (int d = 0; d < 64; ++d) ss += v[d] * v[d];
        const float rs = 1.0f / fmaxf(sqrtf(ss), 1e-12f);
        #pragma unroll
        for (int d = 0; d < 64; ++d) v[d] *= rs;
        uint4* ob = Sbf + ((size_t)(bw << 6) + (col >> 4)) * 128 + (col & 15);
        #pragma unroll
        for (int h = 0; h < 8; ++h)
            ob[h << 4] = pack8cvt(&v[h << 3]);
    }
}

// ---- main: 3-stage hand pipeline, barrier-free, low-occupancy-target --------
// grid 2560 (logical l: qc = l&7, bw = l>>3), block 256 = 4 waves:
// g = wv>>1 (q-group of 4 tiles), h = wv&1 (s-half of 32 tiles).
// Each wave: private 5-slot x 2KB LDS ring; tiles staged 3 ahead.
__global__ __launch_bounds__(256)
__attribute__((amdgpu_waves_per_eu(1, 2)))
void knn_main(const uint4* __restrict__ Qbf,
              const uint4* __restrict__ Sbf,
              const float* __restrict__ rnq,
              float* __restrict__ partial) {
    __shared__ uint4 ring[4][5 * 128];   // 4 waves x 10KB = 40960 B
    const int lin = blockIdx.x;
    const int l   = (lin & 7) * 320 + (lin >> 3);   // 2560 = 8*320, bijective
    const int qc  = l & 7;
    const int bw  = l >> 3;                          // b*5 + w
    const int b   = bw / 5;
    const int wv = threadIdx.x >> 6, lane = threadIdx.x & 63;
    const int g  = wv >> 1, h = wv & 1;

    // Q fragments: q-tiles qc*8 + g*4 + {0..3}
    const uint4* qb = Qbf + ((size_t)(b << 6) + (qc << 3) + (g << 2)) * 128 + lane;
    bf16x8 bq[4][2];
    #pragma unroll
    for (int qt = 0; qt < 4; ++qt)
        #pragma unroll
        for (int c = 0; c < 2; ++c)
            bq[qt][c] = *reinterpret_cast<const bf16x8*>(&qb[qt * 128 + (c << 6)]);

    // wave's global s-range: tiles h*32 .. h*32+31
    const char* sbyte = (const char*)(Sbf + (size_t)bw * 8192) + ((size_t)h << 16)
                        + (size_t)lane * 16;
    uint4* myring = &ring[wv][0];

    float t0[4], t1[4], t2[4];
    #pragma unroll
    for (int qt = 0; qt < 4; ++qt) { t0[qt] = -1e30f; t1[qt] = -1e30f; t2[qt] = -1e30f; }

    auto STAGE = [&](int tile, int slot) {
        gload16(sbyte + (size_t)tile * 2048,        &myring[slot * 128]);
        gload16(sbyte + (size_t)tile * 2048 + 1024, &myring[slot * 128 + 64]);
    };
    auto DSREAD = [&](int slot, bf16x8& a0, bf16x8& a1) {
        a0 = *reinterpret_cast<const bf16x8*>(&myring[slot * 128 + lane]);
        a1 = *reinterpret_cast<const bf16x8*>(&myring[slot * 128 + 64 + lane]);
    };
    auto MFMA4 = [&](const bf16x8& a0, const bf16x8& a1, f32x4 (&c)[4]) {
        #pragma unroll
        for (int qt = 0; qt < 4; ++qt) {
            const f32x4 z = {0.f, 0.f, 0.f, 0.f};
            c[qt] = __builtin_amdgcn_mfma_f32_16x16x32_bf16(a0, bq[qt][0], z, 0, 0, 0);
            c[qt] = __builtin_amdgcn_mfma_f32_16x16x32_bf16(a1, bq[qt][1], c[qt], 0, 0, 0);
        }
    };
    auto INS4 = [&](const f32x4 (&c)[4]) {
        #pragma unroll
        for (int qt = 0; qt < 4; ++qt) {
            INS(c[qt][0], t0[qt], t1[qt], t2[qt]);
            INS(c[qt][1], t0[qt], t1[qt], t2[qt]);
            INS(c[qt][2], t0[qt], t1[qt], t2[qt]);
            INS(c[qt][3], t0[qt], t1[qt], t2[qt]);
        }
    };

    bf16x8 aC0, aC1, aN0, aN1;
    f32x4 cP[4], cN[4];

    // prologue: stage 0..2; read tile0; stage 3; read tile1; MFMA tile0
    STAGE(0, 0); STAGE(1, 1); STAGE(2, 2);
    asm volatile("s_waitcnt vmcnt(4)" ::: "memory");   // tile 0 complete
    DSREAD(0, aC0, aC1);
    STAGE(3, 3);
    asm volatile("s_waitcnt vmcnt(4)" ::: "memory");   // tile 1 complete
    DSREAD(1, aN0, aN1);
    MFMA4(aC0, aC1, cP);                               // tile 0
    aC0 = aN0; aC1 = aN1;

    // main: tiles 1..30, fully unrolled, static slots (tile mod 5)
    #pragma unroll
    for (int t = 1; t <= 30; ++t) {
        if (t + 3 < 32) STAGE(t + 3, (t + 3) % 5);
        if (t <= 28)      { asm volatile("s_waitcnt vmcnt(4)" ::: "memory"); }
        else if (t == 29) { asm volatile("s_waitcnt vmcnt(2)" ::: "memory"); }
        else              { asm volatile("s_waitcnt vmcnt(0)" ::: "memory"); }
        DSREAD((t + 1) % 5, aN0, aN1);                 // prefetch tile t+1
        MFMA4(aC0, aC1, cN);                           // tile t
        INS4(cP);                                      // tile t-1
        #pragma unroll
        for (int qt = 0; qt < 4; ++qt) cP[qt] = cN[qt];
        aC0 = aN0; aC1 = aN1;
    }
    // epilogue: aC holds tile 31; cP holds tile 30
    MFMA4(aC0, aC1, cN);                               // tile 31
    INS4(cP);                                          // tile 30
    INS4(cN);                                          // tile 31

    // merge top-3 across the 4 lane-groups sharing each q
    #pragma unroll
    for (int qt = 0; qt < 4; ++qt) {
        #pragma unroll
        for (int m = 16; m <= 32; m <<= 1) {
            float b0 = __shfl_xor(t0[qt], m);
            float b1 = __shfl_xor(t1[qt], m);
            float b2 = __shfl_xor(t2[qt], m);
            INS(b0, t0[qt], t1[qt], t2[qt]);
            INS(b1, t0[qt], t1[qt], t2[qt]);
            INS(b2, t0[qt], t1[qt], t2[qt]);
        }
    }

    // cross-s-half merge: h=1 wave publishes triples into ITS OWN ring region
    if (h == 1) {
        float* tb = (float*)&ring[wv][0];
        if (lane < 16) {
            #pragma unroll
            for (int qt = 0; qt < 4; ++qt) {
                tb[qt * 48 + lane]      = t0[qt];
                tb[qt * 48 + 16 + lane] = t1[qt];
                tb[qt * 48 + 32 + lane] = t2[qt];
            }
        }
    }
    __syncthreads();
    if (h == 0) {
        const float* tb = (const float*)&ring[wv + 1][0];
        float s3 = 0.f;
        #pragma unroll
        for (int qt = 0; qt < 4; ++qt) {
            float u0 = tb[qt * 48 + (lane & 15)];
            float u1 = tb[qt * 48 + 16 + (lane & 15)];
            float u2 = tb[qt * 48 + 32 + (lane & 15)];
            INS(u0, t0[qt], t1[qt], t2[qt]);
            INS(u1, t0[qt], t1[qt], t2[qt]);
            INS(u2, t0[qt], t1[qt], t2[qt]);
            const int qg = (qc << 7) + (g << 6) + (qt << 4) + (lane & 15);
            s3 += (t0[qt] + t1[qt] + t2[qt]) * rnq[(b << 10) + qg];
        }
        #pragma unroll
        for (int m = 1; m < 64; m <<= 1) s3 += __shfl_xor(s3, m);
        s3 *= 0.25f;                   // each q replicated over 4 lane-groups
        if (lane == 0) partial[(size_t)bw * 16 + qc * 2 + g] = s3;
    }
}

__global__ void finalize16(const float* __restrict__ partial, float* __restrict__ out) {
    int i = blockIdx.x * blockDim.x + threadIdx.x;
    if (i < 320) {
        float a = 0.f;
        #pragma unroll
        for (int k = 0; k < 16; ++k) a += partial[16 * i + k];
        out[i] = a;
    }
}

// ============================ fallback path (round-2) ========================
__global__ void norms_kernel(const float* __restrict__ Q, const float* __restrict__ S,
                             float* __restrict__ rnq, float* __restrict__ rns) {
    int gid = blockIdx.x * blockDim.x + threadIdx.x;
    if (gid < 65536) {
        int b = gid >> 10, qi = gid & 1023;
        const float* p = Q + (size_t)b * 65536 + qi;
        float ss = 0.f;
        #pragma unroll
        for (int d = 0; d < 64; ++d) { float v = p[(size_t)d * 1024]; ss += v * v; }
        rnq[gid] = 1.0f / fmaxf(sqrtf(ss), 1e-12f);
    } else {
        int v = gid - 65536;
        int bw = v >> 10, si = v & 1023;
        const float* p = S + (size_t)bw * 65536 + si;
        float ss = 0.f;
        #pragma unroll
        for (int d = 0; d < 64; ++d) { float x = p[(size_t)d * 1024]; ss += x * x; }
        rns[v] = 1.0f / fmaxf(sqrtf(ss), 1e-12f);
    }
}

__global__ __launch_bounds__(512, 4) void knn_fb(
        const float* __restrict__ Q, const float* __restrict__ S,
        const float* __restrict__ rnq, const float* __restrict__ rns,
        float* __restrict__ partial) {
    __shared__ uint4 qfrag[16 * 128];
    __shared__ uint4 sfrag[2][4 * 128];
    __shared__ float wsum[8];

    const int qc = blockIdx.x, w = blockIdx.y, b = blockIdx.z;
    const int t = threadIdx.x, wv = t >> 6, lane = t & 63;

    const float* Qb   = Q + (size_t)b * 65536;
    const float* Sb   = S + (size_t)(b * 5 + w) * 65536;
    const float* rnqb = rnq + (b << 10);
    const float* rnsb = rns + ((b * 5 + w) << 10);

    bf16x8 bq[4][2];
    for (int ph = 0; ph < 2; ++ph) {
        for (int sub = 0; sub < 4; ++sub) {
            int qg = (qc << 9) + (ph << 8) + (sub << 6) + lane;
            float v[8];
            #pragma unroll
            for (int i = 0; i < 8; ++i)
                v[i] = Qb[(size_t)((wv << 3) + i) * 1024 + qg];
            qfrag[((sub << 2) + (lane >> 4)) * 128 + (wv << 4) + (lane & 15)] = pack8cvt(v);
        }
        __syncthreads();
        if ((wv >> 2) == ph) {
            #pragma unroll
            for (int qt = 0; qt < 4; ++qt)
                #pragma unroll
                for (int c = 0; c < 2; ++c)
                    bq[qt][c] = *reinterpret_cast<const bf16x8*>(
                        &qfrag[(((wv & 3) << 2) + qt) * 128 + (c << 6) + lane]);
        }
        __syncthreads();
    }

    {
        float sv[8]; float rs = rnsb[lane];
        #pragma unroll
        for (int i = 0; i < 8; ++i)
            sv[i] = Sb[(size_t)((wv << 3) + i) * 1024 + lane] * rs;
        sfrag[0][(lane >> 4) * 128 + (wv << 4) + (lane & 15)] = pack8cvt(sv);
    }
    __syncthreads();

    float t0[4], t1[4], t2[4];
    #pragma unroll
    for (int qt = 0; qt < 4; ++qt) { t0[qt] = -1e30f; t1[qt] = -1e30f; t2[qt] = -1e30f; }
    int cur = 0;
    const float* sp = Sb + ((wv << 3) << 10) + lane;

    for (int blk = 0; blk < 16; ++blk) {
        float sv[8]; float rs;
        if (blk < 15) {
            const int sb_ = (blk + 1) << 6;
            rs = rnsb[sb_ + lane];
            #pragma unroll
            for (int i = 0; i < 8; ++i)
                sv[i] = sp[(size_t)(i << 10) + sb_];
        }
        #pragma unroll
        for (int st = 0; st < 4; ++st) {
            bf16x8 a0 = *reinterpret_cast<const bf16x8*>(&sfrag[cur][st * 128 + lane]);
            bf16x8 a1 = *reinterpret_cast<const bf16x8*>(&sfrag[cur][st * 128 + 64 + lane]);
            #pragma unroll
            for (int qt = 0; qt < 4; ++qt) {
                f32x4 c = {0.f, 0.f, 0.f, 0.f};
                c = __builtin_amdgcn_mfma_f32_16x16x32_bf16(a0, bq[qt][0], c, 0, 0, 0);
                c = __builtin_amdgcn_mfma_f32_16x16x32_bf16(a1, bq[qt][1], c, 0, 0, 0);
                #pragma unroll
                for (int j = 0; j < 4; ++j)
                    INS(c[j], t0[qt], t1[qt], t2[qt]);
            }
        }
        if (blk < 15) {
            #pragma unroll
            for (int i = 0; i < 8; ++i) sv[i] *= rs;
            sfrag[cur ^ 1][(lane >> 4) * 128 + (wv << 4) + (lane & 15)] = pack8cvt(sv);
        }
        __syncthreads();
        cur ^= 1;
    }

    float s3 = 0.f;
    #pragma unroll
    for (int qt = 0; qt < 4; ++qt) {
        #pragma unroll
        for (int m = 16; m <= 32; m <<= 1) {
            float b0 = __shfl_xor(t0[qt], m);
            float b1 = __shfl_xor(t1[qt], m);
            float b2 = __shfl_xor(t2[qt], m);
            INS(b0, t0[qt], t1[qt], t2[qt]);
            INS(b1, t0[qt], t1[qt], t2[qt]);
            INS(b2, t0[qt], t1[qt], t2[qt]);
        }
        int qg = (qc << 9) + (wv << 6) + (qt << 4) + (lane & 15);
        s3 += (t0[qt] + t1[qt] + t2[qt]) * rnqb[qg];
    }
    #pragma unroll
    for (int m = 1; m < 64; m <<= 1) s3 += __shfl_xor(s3, m);
    s3 *= 0.25f;
    if (lane == 0) wsum[wv] = s3;
    __syncthreads();
    if (t == 0) {
        float acc = 0.f;
        #pragma unroll
        for (int i = 0; i < 8; ++i) acc += wsum[i];
        partial[((b * 5 + w) << 1) + qc] = acc;
    }
}

__global__ void finalize2(const float* __restrict__ partial, float* __restrict__ out) {
    int i = blockIdx.x * blockDim.x + threadIdx.x;
    if (i < 320)
        out[i] = partial[2 * i] + partial[2 * i + 1];
}

// =============================================================================
extern "C" void kernel_launch(void* const* d_in, const int* in_sizes, int n_in,
                              void* d_out, int out_size, void* d_ws, size_t ws_size,
                              hipStream_t stream) {
    const float* Q = (const float*)d_in[0];   // (64,64,32,32)
    const float* S = (const float*)d_in[1];   // (64,5,64,1024)
    float* out = (float*)d_out;               // (64,5)

    // fast-path ws: Qbf 8 MB | Sbf 41.9 MB | rnq 256 KB | partial 20 KB
    const size_t QBF = 8388608ull, SBF = 41943040ull, RNQ = 262144ull;
    const size_t NEED = QBF + SBF + RNQ + 20480ull;
    if (ws_size >= NEED) {
        char* base = (char*)d_ws;
        uint4* Qbf     = (uint4*)base;
        uint4* Sbf     = (uint4*)(base + QBF);
        float* rnq     = (float*)(base + QBF + SBF);
        float* partial = (float*)(base + QBF + SBF + RNQ);
        prep_all<<<1536, 256, 0, stream>>>(Q, S, Qbf, Sbf, rnq);
        knn_main<<<2560, 256, 0, stream>>>(Qbf, Sbf, rnq, partial);
        finalize16<<<2, 256, 0, stream>>>(partial, out);
    } else {
        float* rnq = (float*)d_ws;
        float* rns = rnq + 65536;
        float* partial = rns + 327680;
        norms_kernel<<<(65536 + 327680) / 256, 256, 0, stream>>>(Q, S, rnq, rns);
        knn_fb<<<dim3(2, 5, 64), 512, 0, stream>>>(Q, S, rnq, rns, partial);
        finalize2<<<2, 256, 0, stream>>>(partial, out);
    }
}